// Round 5
// baseline (16595.975 us; speedup 1.0000x reference)
//
#include <hip/hip_runtime.h>
#include <stdint.h>

// GRU: T=1024, B=64, F=256, H=512, 3H=1536, M=T*B=65536
// ws layout (bytes):
//   xg  bf16 [65536][1536] @ 0          (201,326,592)
//   xbf bf16 [65536][256]  @ 201326592  (33,554,432)
//   wit bf16 [1536][256]   @ 234881024  (786,432)     = Wi^T
//   wht bf16 [1536][512]   @ 235667456  (1,572,864)   = Wh^T
//   hsf u32 [2][64][512]   @ 237240320  (262,144)     stamped h: (stamp<<16)|bf16
//                                                     self-synchronizing words;
//                                                     NO flags, NO barrier.
#define NB 32  // scan blocks; must all be co-resident (32 << 256 CUs)

typedef __attribute__((ext_vector_type(8))) short short8;
typedef __attribute__((ext_vector_type(4))) float floatx4;

__device__ __forceinline__ unsigned short f2bf(float f) {
  unsigned u = __float_as_uint(f);
  u += 0x7fff + ((u >> 16) & 1);  // RNE
  return (unsigned short)(u >> 16);
}
__device__ __forceinline__ float bf2f(unsigned short s) {
  return __uint_as_float(((unsigned)s) << 16);
}

__device__ __forceinline__ unsigned long long ald64(const unsigned* p) {
  return __hip_atomic_load((const unsigned long long*)p,
                           __ATOMIC_RELAXED, __HIP_MEMORY_SCOPE_AGENT);
}

// ---------------- prep: casts + transposes + stamped-h init ----------------
__global__ __launch_bounds__(256) void prep_kernel(
    const float* __restrict__ x, const float* __restrict__ h0,
    const float* __restrict__ Wi, const float* __restrict__ Wh,
    unsigned short* __restrict__ xbf, unsigned short* __restrict__ wit,
    unsigned short* __restrict__ wht, unsigned* __restrict__ hsf) {
  int i = blockIdx.x * 256 + threadIdx.x;
  if (i < 4194304) {                       // x cast, 4 elems/thread
    float4 v = ((const float4*)x)[i];
    ushort4 o;
    o.x = f2bf(v.x); o.y = f2bf(v.y); o.z = f2bf(v.z); o.w = f2bf(v.w);
    ((ushort4*)xbf)[i] = o;
  } else if (i < 4587520) {                // Wi^T: wit[n*256+k] = Wi[k*1536+n]
    int j = i - 4194304;
    int n = j >> 8, k = j & 255;
    wit[j] = f2bf(Wi[(size_t)k * 1536 + n]);
  } else if (i < 5373952) {                // Wh^T: wht[n*512+k] = Wh[k*1536+n]
    int j = i - 4587520;
    int n = j >> 9, k = j & 511;
    wht[j] = f2bf(Wh[(size_t)k * 1536 + n]);
  } else if (i < 5406720) {                // hsf[0] = stamp0 | bf16(h0)
    int j = i - 5373952;
    __hip_atomic_store(&hsf[j], (unsigned)f2bf(h0[j]),
                       __ATOMIC_RELAXED, __HIP_MEMORY_SCOPE_AGENT);
  } else if (i < 5439488) {                // hsf[1] = sentinel (stamp 0xFFFF)
    int j = i - 5406720;
    __hip_atomic_store(&hsf[32768 + j], 0xFFFF0000u,
                       __ATOMIC_RELAXED, __HIP_MEMORY_SCOPE_AGENT);
  }
}

// ---------------- xg = x @ Wi + bi (bf16 MFMA, 128x128 tile) ----------------
__global__ __launch_bounds__(256, 2) void gemm_xg(
    const unsigned short* __restrict__ A,   // [65536][256] bf16
    const unsigned short* __restrict__ BT,  // [1536][256] bf16 (Wi^T)
    const float* __restrict__ bi,
    unsigned short* __restrict__ C) {       // [65536][1536] bf16
  __shared__ __align__(16) unsigned short lA[128 * 72];  // +8 pad
  __shared__ __align__(16) unsigned short lB[128 * 72];
  const int tid = threadIdx.x;
  const int w = tid >> 6, lane = tid & 63;
  const int wm = w >> 1, wn = w & 1;
  const int q = lane >> 4, l16 = lane & 15;
  const int bx = blockIdx.x, by = blockIdx.y;

  floatx4 acc[4][4];
#pragma unroll
  for (int a = 0; a < 4; ++a)
#pragma unroll
    for (int b = 0; b < 4; ++b) acc[a][b] = (floatx4){0.f, 0.f, 0.f, 0.f};

  for (int kt = 0; kt < 4; ++kt) {   // K=256 in BK=64 chunks
    if (kt) __syncthreads();
#pragma unroll
    for (int i = 0; i < 4; ++i) {    // stage A,B tiles (16B/lane vec loads)
      int c = tid + i * 256;
      int r = c >> 3, kk = (c & 7) * 8;
      *(uint4*)&lA[r * 72 + kk] =
          *(const uint4*)&A[(size_t)(bx * 128 + r) * 256 + kt * 64 + kk];
      *(uint4*)&lB[r * 72 + kk] =
          *(const uint4*)&BT[(size_t)(by * 128 + r) * 256 + kt * 64 + kk];
    }
    __syncthreads();
#pragma unroll
    for (int ks = 0; ks < 2; ++ks) {
      const int kk = ks * 32 + q * 8;
      short8 af[4], bf[4];
#pragma unroll
      for (int rm = 0; rm < 4; ++rm)
        af[rm] = *(const short8*)&lA[(wm * 64 + rm * 16 + l16) * 72 + kk];
#pragma unroll
      for (int cn = 0; cn < 4; ++cn)
        bf[cn] = *(const short8*)&lB[(wn * 64 + cn * 16 + l16) * 72 + kk];
#pragma unroll
      for (int rm = 0; rm < 4; ++rm)
#pragma unroll
        for (int cn = 0; cn < 4; ++cn)
          acc[rm][cn] = __builtin_amdgcn_mfma_f32_16x16x32_bf16(
              af[rm], bf[cn], acc[rm][cn], 0, 0, 0);
    }
  }
  // epilogue: + bi, store bf16. C layout: col=lane&15, row=q*4+reg
#pragma unroll
  for (int cn = 0; cn < 4; ++cn) {
    const int col = by * 128 + wn * 64 + cn * 16 + l16;
    const float bic = bi[col];
#pragma unroll
    for (int rm = 0; rm < 4; ++rm)
#pragma unroll
      for (int r = 0; r < 4; ++r) {
        const int row = bx * 128 + wm * 64 + rm * 16 + q * 4 + r;
        C[(size_t)row * 1536 + col] = f2bf(acc[rm][cn][r] + bic);
      }
  }
}

// ---------------- persistent GRU scan — barrier-free ----------------
// 32 blocks x 256 thr. Block b owns h dims [b*16, b*16+16).
// h is exchanged as stamped 32-bit words ((t+1)<<16 | bf16): a single dword
// store is atomic, so data and readiness travel together. Consumers poll
// their own operand words for stamp==t. No flags, no __syncthreads.
// Safety: a block writes stamp t+2 only after consuming stamp t+1 from all
// blocks, which implies all finished reading stamp t -> 2 buffers suffice,
// '==' polling cannot deadlock or see future stamps. Cross-launch residue is
// killed by prep's sentinel (0xFFFF) in buffer 1 + harness 0xAA poison.
__global__ __launch_bounds__(256, 1) void scan_kernel(
    const unsigned short* __restrict__ xg,   // [T*B][1536] bf16
    const unsigned short* __restrict__ wht,  // [1536][512] bf16
    const float* __restrict__ h0, const float* __restrict__ bhn,
    float* __restrict__ ys,                  // [T*B][512] f32
    unsigned* __restrict__ hsf) {            // [2][64][512] stamped words
  const int tid = threadIdx.x;
  const int w = tid >> 6, lane = tid & 63;
  const int q = lane >> 4, l16 = lane & 15;
  const int i0 = blockIdx.x * 16;

  // b-frags: lane holds B[k=q*8+j][n=l16] = wht[n][k], 8 consecutive k
  short8 bfr[3][16];
#pragma unroll
  for (int g = 0; g < 3; ++g)
#pragma unroll
    for (int s = 0; s < 16; ++s)
      bfr[g][s] = *(const short8*)
          &wht[(size_t)(g * 512 + i0 + l16) * 512 + s * 32 + q * 8];

  const int dim = i0 + l16;        // C-layout col
  const float bhn_c = bhn[dim];
  const int bc0 = w * 16 + q * 4;  // C-layout rows (batches) bc0..bc0+3
  const int ba = w * 16 + l16;     // A-frag row (batch)

  float hreg[4];
#pragma unroll
  for (int r = 0; r < 4; ++r) hreg[r] = h0[(size_t)(bc0 + r) * 512 + dim];

  for (int t = 0; t < 1024; ++t) {
    const unsigned* src = hsf + (size_t)(t & 1) * 32768;
    unsigned* dst = hsf + (size_t)((t + 1) & 1) * 32768;

    // bulk-issue all staged stamped loads (pipelined in the fabric)
    unsigned long long st[16][4];
#pragma unroll
    for (int s = 0; s < 16; ++s) {
      const unsigned* p = src + ba * 512 + s * 32 + q * 8;
#pragma unroll
      for (int j = 0; j < 4; ++j) st[s][j] = ald64(p + j * 2);
    }
    // xg for this step (plain cached loads; needed only after the MFMA chain)
    float xcur[3][4];
#pragma unroll
    for (int r = 0; r < 4; ++r) {
      size_t xb = ((size_t)t * 64 + bc0 + r) * 1536 + dim;
      xcur[0][r] = bf2f(xg[xb]);
      xcur[1][r] = bf2f(xg[xb + 512]);
      xcur[2][r] = bf2f(xg[xb + 1024]);
    }

    const unsigned e = ((unsigned)t) << 16;
    floatx4 a0 = {0.f, 0.f, 0.f, 0.f};
    floatx4 a1 = {0.f, 0.f, 0.f, 0.f};
    floatx4 a2 = {0.f, 0.f, 0.f, 0.f};
#pragma unroll
    for (int s = 0; s < 16; ++s) {
      unsigned long long v0 = st[s][0], v1 = st[s][1];
      unsigned long long v2 = st[s][2], v3 = st[s][3];
      for (;;) {
        unsigned m = ((unsigned)v0 ^ e) | ((unsigned)(v0 >> 32) ^ e) |
                     ((unsigned)v1 ^ e) | ((unsigned)(v1 >> 32) ^ e) |
                     ((unsigned)v2 ^ e) | ((unsigned)(v2 >> 32) ^ e) |
                     ((unsigned)v3 ^ e) | ((unsigned)(v3 >> 32) ^ e);
        if (__ballot((m & 0xffff0000u) == 0u) == ~0ull) break;
        const unsigned* p = src + ba * 512 + s * 32 + q * 8;
        v0 = ald64(p); v1 = ald64(p + 2); v2 = ald64(p + 4); v3 = ald64(p + 6);
      }
      union { unsigned u[4]; short8 s8; } pk;  // strip stamps -> bf16x8
      pk.u[0] = ((unsigned)v0 & 0xffffu) | ((unsigned)(v0 >> 32) << 16);
      pk.u[1] = ((unsigned)v1 & 0xffffu) | ((unsigned)(v1 >> 32) << 16);
      pk.u[2] = ((unsigned)v2 & 0xffffu) | ((unsigned)(v2 >> 32) << 16);
      pk.u[3] = ((unsigned)v3 & 0xffffu) | ((unsigned)(v3 >> 32) << 16);
      a0 = __builtin_amdgcn_mfma_f32_16x16x32_bf16(pk.s8, bfr[0][s], a0, 0, 0, 0);
      a1 = __builtin_amdgcn_mfma_f32_16x16x32_bf16(pk.s8, bfr[1][s], a1, 0, 0, 0);
      a2 = __builtin_amdgcn_mfma_f32_16x16x32_bf16(pk.s8, bfr[2][s], a2, 0, 0, 0);
    }

    const unsigned ns = ((unsigned)(t + 1)) << 16;
#pragma unroll
    for (int r = 0; r < 4; ++r) {
      const int bc = bc0 + r;
      float rg = 1.f / (1.f + __expf(-(xcur[0][r] + a0[r])));
      float zg = 1.f / (1.f + __expf(-(xcur[1][r] + a1[r])));
      float pre = xcur[2][r] + rg * (a2[r] + bhn_c);
      pre = fminf(fmaxf(pre, -15.f), 15.f);  // avoid inf/inf NaN in tanh
      float e2 = __expf(2.f * pre);
      float ng = (e2 - 1.f) / (e2 + 1.f);
      float hnew = (1.f - zg) * ng + zg * hreg[r];
      hreg[r] = hnew;
      if (t != 1023)   // stamped self-synchronizing publish (fire-and-forget)
        __hip_atomic_store(&dst[(size_t)bc * 512 + dim], ns | f2bf(hnew),
                           __ATOMIC_RELAXED, __HIP_MEMORY_SCOPE_AGENT);
      ys[((size_t)t * 64 + bc) * 512 + dim] = hnew;
    }
  }
}

extern "C" void kernel_launch(void* const* d_in, const int* in_sizes, int n_in,
                              void* d_out, int out_size, void* d_ws, size_t ws_size,
                              hipStream_t stream) {
  const float* x   = (const float*)d_in[0];
  const float* h0  = (const float*)d_in[1];
  const float* Wi  = (const float*)d_in[2];
  const float* bi  = (const float*)d_in[3];
  const float* Wh  = (const float*)d_in[4];
  const float* bhn = (const float*)d_in[5];
  float* ys = (float*)d_out;

  char* ws = (char*)d_ws;
  unsigned short* xg  = (unsigned short*)(ws);
  unsigned short* xbf = (unsigned short*)(ws + 201326592);
  unsigned short* wit = (unsigned short*)(ws + 234881024);
  unsigned short* wht = (unsigned short*)(ws + 235667456);
  unsigned*       hsf = (unsigned*)(ws + 237240320);

  prep_kernel<<<21248, 256, 0, stream>>>(x, h0, Wi, Wh, xbf, wit, wht, hsf);
  gemm_xg<<<dim3(512, 12), 256, 0, stream>>>(xbf, wit, bi, xg);
  scan_kernel<<<NB, 256, 0, stream>>>(xg, wht, h0, bhn, ys, hsf);
}